// Round 8
// baseline (539.184 us; speedup 1.0000x reference)
//
#include <hip/hip_runtime.h>
#include <cstdint>
#include <cstddef>

// SwinBlock3D: LN1 -> roll(-1,-3,-3) -> window(2,7,7) attn (12 heads, rel-bias)
// -> proj + resid -> LN2 -> MLP(384->1536 gelu ->384) + resid.
// bf16 MFMA matmuls; fp32 LN/softmax/final residual; bf16 s1 intermediate.
// GEMM v4 (T3 "minimum 2-phase", 256x128, 8 waves): one barrier per K-tile;
// stage(t+1) issued BEFORE the 32-MFMA cluster, vmcnt(0) drained AFTER it
// (hides L2 latency under MFMA -- R5's bug was draining at tile top).

typedef __bf16 bf16x8 __attribute__((ext_vector_type(8)));
typedef __bf16 bf16x4 __attribute__((ext_vector_type(4)));
typedef float f32x4 __attribute__((ext_vector_type(4)));

#define DIM 384
#define QKV_DIM 1152
#define HID 1536
#define NHEADS 12
#define NTOK 50176
#define NWIN 512

// async global->LDS, 16B per lane; LDS dest = wave-uniform base + lane*16
__device__ __forceinline__ void gload16(const void* g, void* s) {
  __builtin_amdgcn_global_load_lds(
      (const __attribute__((address_space(1))) void*)g,
      (__attribute__((address_space(3))) void*)s, 16, 0, 0);
}

// ---------------- prep kernels ----------------
__global__ __launch_bounds__(256) void build_tokmap_k(int* __restrict__ map) {
  int t = blockIdx.x * 256 + threadIdx.x;
  if (t >= NTOK) return;
  int win = t / 98, n = t - win * 98;
  int b = win >> 8, tw = (win >> 6) & 3, hw = (win >> 3) & 7, ww = win & 7;
  int dt = n / 49; int rem = n - dt * 49; int dh = rem / 7, dw = rem - dh * 7;
  int t0 = (tw * 2 + dt + 1) & 7;                 // roll by shift (1,3,3)
  int h0 = hw * 7 + dh + 3; if (h0 >= 56) h0 -= 56;
  int w0 = ww * 7 + dw + 3; if (w0 >= 56) w0 -= 56;
  map[t] = ((b * 8 + t0) * 56 + h0) * 56 + w0;    // spatial row for window-token t
}

// packed bias in MFMA-fragment order: pb[h][mi][ni][lane][r], j>=98 mask pre-baked
__global__ __launch_bounds__(256) void expand_biasp_k(const float* __restrict__ table,
                                                      const int* __restrict__ rel,
                                                      float* __restrict__ out) {
  int e = blockIdx.x * 256 + threadIdx.x;
  if (e >= NHEADS * 49 * 256) return;
  int r = e & 3, l = (e >> 2) & 63;
  int rest = e >> 8;
  int ni = rest % 7, mi = (rest / 7) % 7, h = rest / 49;
  int i = mi * 16 + (l >> 4) * 4 + r;
  int j = ni * 16 + (l & 15);
  float v;
  if (j >= 98) v = -1e30f;          // pad-column mask baked in
  else if (i >= 98) v = 0.f;
  else v = table[rel[i * 98 + j] * NHEADS + h];
  out[e] = v;
}

__global__ __launch_bounds__(256) void transpose_w_k(const float* __restrict__ W,
                                                     __bf16* __restrict__ WT,
                                                     int K, int N, int scaleCols, float scale) {
  int e = blockIdx.x * 256 + threadIdx.x;
  if (e >= K * N) return;
  int n = e / K, k = e - n * K;
  float v = W[(size_t)k * N + n];
  if (n < scaleCols) v *= scale;                  // fold q-scale into W_q
  WT[e] = (__bf16)v;                              // WT[n][k]
}

__global__ __launch_bounds__(256) void scale_bias_k(const float* __restrict__ b,
                                                    float* __restrict__ out,
                                                    int n, int scaleCols, float scale) {
  int e = blockIdx.x * 256 + threadIdx.x;
  if (e >= n) return;
  out[e] = b[e] * (e < scaleCols ? scale : 1.0f);
}

// V^T: vt[(win*12+h)*32 + d][tok 0..127] bf16, zeros past tok 97
__global__ __launch_bounds__(384) void vtrans_k(const __bf16* __restrict__ qkv,
                                                __bf16* __restrict__ vt) {
  int win = blockIdx.x, t = threadIdx.x;          // t = h*32+d
  const __bf16* base = qkv + (size_t)win * 98 * QKV_DIM + 768 + t;
  __bf16* orow = vt + ((size_t)win * 384 + t) * 128;
  #pragma unroll
  for (int c = 0; c < 16; ++c) {
    bf16x8 pk;
    #pragma unroll
    for (int e2 = 0; e2 < 8; ++e2) {
      int tok = c * 8 + e2;
      pk[e2] = (tok < 98) ? base[(size_t)tok * QKV_DIM] : (__bf16)0.f;
    }
    *(bf16x8*)(orow + c * 8) = pk;
  }
}

// ---------------- layernorm (1 wave per token row of 384) ----------------
template <typename T>
__global__ __launch_bounds__(256) void ln_k(const T* __restrict__ x,
                                            const float* __restrict__ g,
                                            const float* __restrict__ bta,
                                            __bf16* __restrict__ out,
                                            const int* __restrict__ map) {
  int w = threadIdx.x >> 6, l = threadIdx.x & 63;
  int tok = blockIdx.x * 4 + w;
  int src = map ? map[tok] : tok;
  const T* row = x + (size_t)src * DIM;
  float v[6]; float s = 0.f;
  #pragma unroll
  for (int j = 0; j < 6; ++j) { v[j] = (float)row[l + 64 * j]; s += v[j]; }
  #pragma unroll
  for (int m = 1; m < 64; m <<= 1) s += __shfl_xor(s, m, 64);
  float mu = s * (1.f / DIM);
  float var = 0.f;
  #pragma unroll
  for (int j = 0; j < 6; ++j) { float d = v[j] - mu; var += d * d; }
  #pragma unroll
  for (int m = 1; m < 64; m <<= 1) var += __shfl_xor(var, m, 64);
  float rs = rsqrtf(var * (1.f / DIM) + 1e-5f);
  __bf16* orow = out + (size_t)tok * DIM;
  #pragma unroll
  for (int j = 0; j < 6; ++j) {
    int c = l + 64 * j;
    orow[c] = (__bf16)((v[j] - mu) * rs * g[c] + bta[c]);
  }
}

// ------- 256x128 bf16 MFMA GEMM, BK=64, 8 waves (4M x 2N), 2-phase T3 -------
// A[M][K], BT[N][K] bf16 row-major, both staged via global_load_lds with
// pre-swizzled global source chunk ((t&7)^((t>>3)&7)); LDS dest linear;
// ds_read col = (ck ^ (row&7)).  LDS: [A0 32K][B0 16K][A1 32K][B1 16K].
// Per K-tile: STAGE(t+1) -> 16 ds_read -> lgkmcnt(0)+sched_barrier ->
// setprio(1) 32 MFMA setprio(0) -> vmcnt(0) -> s_barrier.  ONE barrier/tile.
// MFMA operands swapped -> C^T fragments -> vectorized epilogue.
// EPI: 0 = +bias -> bf16   1 = +bias + residf(x fp32), scatter tokmap -> bf16
//      2 = +bias, fast-gelu -> bf16   3 = +bias + residb(bf16) -> fp32
template <int EPI>
__global__ __launch_bounds__(512, 1) void gemm_k(const __bf16* __restrict__ A,
                                                 const __bf16* __restrict__ BT,
                                                 const float* __restrict__ bias,
                                                 int M, int N, int K,
                                                 __bf16* __restrict__ outb,
                                                 float* __restrict__ outf,
                                                 const float* __restrict__ residf,
                                                 const __bf16* __restrict__ residb,
                                                 const int* __restrict__ tokmap) {
  __shared__ __align__(1024) char lds[98304];
  const int tid = threadIdx.x;
  const int l = tid & 63, w = tid >> 6;
  const int lr = l & 15, lg = l >> 4;
  const int wm = w >> 1, wn = w & 1;
  const int ntile = N >> 7;
  // bijective XCD swizzle (m204) -- grids here are not all %8
  const int nwg = gridDim.x, qd = nwg >> 3, rm = nwg & 7;
  const int xcd = blockIdx.x & 7;
  const int wgid = (xcd < rm ? xcd * (qd + 1) : rm * (qd + 1) + (xcd - rm) * qd)
                   + (blockIdx.x >> 3);
  const int bm = wgid / ntile, bn = wgid - bm * ntile;
  const int m0 = bm << 8, n0 = bn << 7;
  // staging geometry: thread t covers row t>>3 (of a 64-row sweep), chunk t&7
  const int srow = tid >> 3;
  const int sch = (tid & 7) ^ (srow & 7);
  const __bf16* pa = A + (size_t)(m0 + srow) * K + sch * 8;   // + sweep*64 rows
  const __bf16* pb = BT + (size_t)(n0 + srow) * K + sch * 8;
  const int dofs = (w << 10);                     // wave-uniform LDS base part
  const int nk = K >> 6;

#define STAGE(buf, kt)                                                        \
  {                                                                           \
    const size_t ko = (size_t)(kt) << 6;                                      \
    char* ab_ = lds + (buf) * 49152;                                          \
    _Pragma("unroll")                                                         \
    for (int s_ = 0; s_ < 4; ++s_)                                            \
      gload16(pa + (size_t)(s_ * 64) * K + ko, ab_ + s_ * 8192 + dofs);       \
    _Pragma("unroll")                                                         \
    for (int s_ = 0; s_ < 2; ++s_)                                            \
      gload16(pb + (size_t)(s_ * 64) * K + ko, ab_ + 32768 + s_ * 8192 + dofs);\
  }

  // prologue: tile 0 -> buffer 0
  STAGE(0, 0)
  asm volatile("s_waitcnt vmcnt(0)" ::: "memory");
  asm volatile("s_barrier" ::: "memory");

  f32x4 acc[4][4] = {};
  int cur = 0;
  for (int kt = 0; kt < nk; ++kt) {
    const bool pf = (kt + 1 < nk);
    if (pf) STAGE(cur ^ 1, kt + 1)                // issue next tile's stage first
    const char* ab = lds + cur * 49152;
    const char* bb = ab + 32768;
    bf16x8 af[4][2], bf[4][2];
    #pragma unroll
    for (int kk = 0; kk < 2; ++kk) {
      const int ck = (kk << 2) + lg;
      #pragma unroll
      for (int m = 0; m < 4; ++m) {
        int r = (wm << 6) + (m << 4) + lr;
        af[m][kk] = *(const bf16x8*)(ab + (r << 7) + ((ck ^ (r & 7)) << 4));
      }
      #pragma unroll
      for (int n = 0; n < 4; ++n) {
        int r = (wn << 6) + (n << 4) + lr;
        bf[n][kk] = *(const bf16x8*)(bb + (r << 7) + ((ck ^ (r & 7)) << 4));
      }
    }
    asm volatile("s_waitcnt lgkmcnt(0)" ::: "memory");
    __builtin_amdgcn_sched_barrier(0);            // rule 18: pin MFMA after wait
    __builtin_amdgcn_s_setprio(1);
    #pragma unroll
    for (int kk = 0; kk < 2; ++kk)
      #pragma unroll
      for (int m = 0; m < 4; ++m)
        #pragma unroll
        for (int n = 0; n < 4; ++n)   // swapped operands -> C^T fragment layout
          acc[m][n] = __builtin_amdgcn_mfma_f32_16x16x32_bf16(bf[n][kk], af[m][kk],
                                                              acc[m][n], 0, 0, 0);
    __builtin_amdgcn_s_setprio(0);
    if (pf) asm volatile("s_waitcnt vmcnt(0)" ::: "memory");  // t+1 landed (hidden)
    asm volatile("s_barrier" ::: "memory");
    cur ^= 1;
  }
#undef STAGE

  // epilogue (C^T frags): row = m0+wm*64+m*16+lr, cols = n0+wn*64+n*16+lg*4..+3
  #pragma unroll
  for (int m = 0; m < 4; ++m) {
    const int grow = m0 + (wm << 6) + (m << 4) + lr;
    #pragma unroll
    for (int n = 0; n < 4; ++n) {
      const int gcol = n0 + (wn << 6) + (n << 4) + (lg << 2);
      f32x4 a = acc[m][n] + *(const f32x4*)(bias + gcol);
      if (EPI == 0) {
        bf16x4 c;
        #pragma unroll
        for (int r = 0; r < 4; ++r) c[r] = (__bf16)a[r];
        *(bf16x4*)(outb + (size_t)grow * N + gcol) = c;
      } else if (EPI == 1) {
        int dst = tokmap[grow];
        f32x4 rv = *(const f32x4*)(residf + (size_t)dst * DIM + gcol);
        bf16x4 c;
        #pragma unroll
        for (int r = 0; r < 4; ++r) c[r] = (__bf16)(rv[r] + a[r]);
        *(bf16x4*)(outb + (size_t)dst * DIM + gcol) = c;
      } else if (EPI == 2) {
        bf16x4 c;
        #pragma unroll
        for (int r = 0; r < 4; ++r) {
          float vv = a[r];
          float y = vv * (1.0f + 0.044715f * vv * vv);
          c[r] = (__bf16)(vv / (1.0f + __expf(-1.5957691216057308f * y)));
        }
        *(bf16x4*)(outb + (size_t)grow * N + gcol) = c;
      } else {
        bf16x4 sv = *(const bf16x4*)(residb + (size_t)grow * N + gcol);
        f32x4 o;
        #pragma unroll
        for (int r = 0; r < 4; ++r) o[r] = (float)sv[r] + a[r];
        *(f32x4*)(outf + (size_t)grow * N + gcol) = o;
      }
    }
  }
}

// ---------------- window attention: 1 wave per (window, head, mi-tile) ------
__global__ __launch_bounds__(64) void attn_k(const __bf16* __restrict__ qkv,
                                             const __bf16* __restrict__ vt,
                                             const float* __restrict__ pb,
                                             __bf16* __restrict__ out) {
  __shared__ __align__(1024) char P[4096];
  const int l = threadIdx.x, lr = l & 15, lg = l >> 4;
  const int bid = blockIdx.x;
  const int xc = bid & 7, kk = bid >> 3;
  const int wh = (kk / 7) * 8 + xc, mi = kk % 7;
  const int win = wh / NHEADS, h = wh - win * NHEADS;
  const size_t wbase = (size_t)win * 98 * QKV_DIM;
  const __bf16* qb = qkv + wbase + h * 32;
  const __bf16* kb = qb + 384;
  const bf16x8 z8 = {};
  const f32x4 fz = {};

  bf16x8 kf[7];
  #pragma unroll
  for (int ni = 0; ni < 7; ++ni) {
    int tok = ni * 16 + lr;
    kf[ni] = (tok < 98) ? *(const bf16x8*)(kb + (size_t)tok * QKV_DIM + lg * 8) : z8;
  }
  int qt = mi * 16 + lr;
  bf16x8 qf = (qt < 98) ? *(const bf16x8*)(qb + (size_t)qt * QKV_DIM + lg * 8) : z8;
  const f32x4* pbp = (const f32x4*)pb + (size_t)((h * 7 + mi) * 7) * 64 + l;
  f32x4 bv[7];
  #pragma unroll
  for (int ni = 0; ni < 7; ++ni) bv[ni] = pbp[ni * 64];

  f32x4 s[7];
  #pragma unroll
  for (int ni = 0; ni < 7; ++ni)
    s[ni] = __builtin_amdgcn_mfma_f32_16x16x32_bf16(qf, kf[ni], fz, 0, 0, 0);

  if (l < 32) {
    int row = l >> 1, c = 14 + (l & 1);
    *(f32x4*)(P + row * 256 + ((c ^ (row & 7)) << 4)) = fz;
  }

  #pragma unroll
  for (int r = 0; r < 4; ++r) {
    float mx = -1e30f;
    #pragma unroll
    for (int ni = 0; ni < 7; ++ni) {
      float vv = s[ni][r] + bv[ni][r];
      s[ni][r] = vv;
      mx = fmaxf(mx, vv);
    }
    #pragma unroll
    for (int m2 = 1; m2 < 16; m2 <<= 1) mx = fmaxf(mx, __shfl_xor(mx, m2, 64));
    float sum = 0.f;
    #pragma unroll
    for (int ni = 0; ni < 7; ++ni) { float p = __expf(s[ni][r] - mx); s[ni][r] = p; sum += p; }
    #pragma unroll
    for (int m2 = 1; m2 < 16; m2 <<= 1) sum += __shfl_xor(sum, m2, 64);
    float inv = 1.0f / sum;
    int il = lg * 4 + r;
    #pragma unroll
    for (int ni = 0; ni < 7; ++ni) {
      int j = ni * 16 + lr;
      *(__bf16*)(P + il * 256 + (((j >> 3) ^ (il & 7)) << 4) + ((j & 7) << 1)) =
          (__bf16)(s[ni][r] * inv);
    }
  }
  __syncthreads();

  bf16x8 pa[4];
  #pragma unroll
  for (int ks = 0; ks < 4; ++ks) {
    int ck = ks * 4 + lg;
    pa[ks] = *(const bf16x8*)(P + lr * 256 + ((ck ^ (lr & 7)) << 4));
  }
  const __bf16* vrow = vt + ((size_t)wh * 32) * 128;
  __bf16* ob = out + ((size_t)win * 98 + mi * 16) * DIM + h * 32;
  #pragma unroll
  for (int nf = 0; nf < 2; ++nf) {
    int d = nf * 16 + lr;
    f32x4 o = fz;
    #pragma unroll
    for (int ks = 0; ks < 4; ++ks) {
      bf16x8 vb = *(const bf16x8*)(vrow + (size_t)d * 128 + ks * 32 + lg * 8);
      o = __builtin_amdgcn_mfma_f32_16x16x32_bf16(pa[ks], vb, o, 0, 0, 0);
    }
    #pragma unroll
    for (int r = 0; r < 4; ++r) {
      int il = lg * 4 + r;
      if (mi * 16 + il < 98) ob[(size_t)il * DIM + nf * 16 + lr] = (__bf16)o[r];
    }
  }
}

// ---------------- launch ----------------
extern "C" void kernel_launch(void* const* d_in, const int* in_sizes, int n_in,
                              void* d_out, int out_size, void* d_ws, size_t ws_size,
                              hipStream_t stream) {
  const float* x      = (const float*)d_in[0];
  const float* n1g    = (const float*)d_in[1];
  const float* n1b    = (const float*)d_in[2];
  const float* qkv_w  = (const float*)d_in[3];
  const float* qkv_b  = (const float*)d_in[4];
  const float* proj_w = (const float*)d_in[5];
  const float* proj_b = (const float*)d_in[6];
  const float* btab   = (const float*)d_in[7];
  const float* n2g    = (const float*)d_in[8];
  const float* n2b    = (const float*)d_in[9];
  const float* fc1_w  = (const float*)d_in[10];
  const float* fc1_b  = (const float*)d_in[11];
  const float* fc2_w  = (const float*)d_in[12];
  const float* fc2_b  = (const float*)d_in[13];
  const int*   relidx = (const int*)d_in[14];
  float* outp = (float*)d_out;
  (void)in_sizes; (void)n_in; (void)out_size; (void)ws_size;

  char* ws = (char*)d_ws;
  size_t off = 0;
  auto alloc = [&](size_t bytes) {
    char* p = ws + off;
    off = (off + bytes + 255) & ~(size_t)255;
    return p;
  };
  int*    tokmap = (int*)alloc((size_t)NTOK * 4);
  float*  biasex = (float*)alloc((size_t)NHEADS * 49 * 256 * 4);
  __bf16* wqkvT  = (__bf16*)alloc((size_t)QKV_DIM * DIM * 2);
  __bf16* wprojT = (__bf16*)alloc((size_t)DIM * DIM * 2);
  __bf16* wfc1T  = (__bf16*)alloc((size_t)HID * DIM * 2);
  __bf16* wfc2T  = (__bf16*)alloc((size_t)DIM * HID * 2);
  float*  qkvbS  = (float*)alloc((size_t)QKV_DIM * 4);
  __bf16* tokens = (__bf16*)alloc((size_t)NTOK * DIM * 2);   // LN1 out / attn out / LN2 out
  __bf16* qkvbuf = (__bf16*)alloc((size_t)NTOK * HID * 2);   // qkv (1152) then h1 (1536)
  __bf16* s1     = (__bf16*)alloc((size_t)NTOK * DIM * 2);   // x + attn-proj, bf16
  __bf16* attnout = tokens;
  __bf16* h1 = qkvbuf;
  // vt (50.3MB) lives in d_out (77MB fp32) — only fc2 writes d_out, at the end
  __bf16* vt = (__bf16*)d_out;

  const float scale = 0.17677669529663687f;  // 1/sqrt(32)

  build_tokmap_k<<<NTOK / 256, 256, 0, stream>>>(tokmap);
  expand_biasp_k<<<(NHEADS * 49 * 256) / 256, 256, 0, stream>>>(btab, relidx, biasex);
  transpose_w_k<<<(DIM * QKV_DIM) / 256, 256, 0, stream>>>(qkv_w, wqkvT, DIM, QKV_DIM, DIM, scale);
  transpose_w_k<<<(DIM * DIM) / 256, 256, 0, stream>>>(proj_w, wprojT, DIM, DIM, 0, 1.0f);
  transpose_w_k<<<(DIM * HID) / 256, 256, 0, stream>>>(fc1_w, wfc1T, DIM, HID, 0, 1.0f);
  transpose_w_k<<<(HID * DIM) / 256, 256, 0, stream>>>(fc2_w, wfc2T, HID, DIM, 0, 1.0f);
  scale_bias_k<<<(QKV_DIM + 255) / 256, 256, 0, stream>>>(qkv_b, qkvbS, QKV_DIM, DIM, scale);

  ln_k<float><<<NTOK / 4, 256, 0, stream>>>(x, n1g, n1b, tokens, tokmap);
  gemm_k<0><<<(NTOK / 256) * (QKV_DIM / 128), 512, 0, stream>>>(
      tokens, wqkvT, qkvbS, NTOK, QKV_DIM, DIM, qkvbuf, nullptr, nullptr, nullptr, nullptr);
  vtrans_k<<<NWIN, 384, 0, stream>>>(qkvbuf, vt);
  attn_k<<<NWIN * NHEADS * 7, 64, 0, stream>>>(qkvbuf, vt, biasex, attnout);
  gemm_k<1><<<(NTOK / 256) * (DIM / 128), 512, 0, stream>>>(
      attnout, wprojT, proj_b, NTOK, DIM, DIM, s1, nullptr, x, nullptr, tokmap);
  ln_k<__bf16><<<NTOK / 4, 256, 0, stream>>>(s1, n2g, n2b, tokens, nullptr);
  gemm_k<2><<<(NTOK / 256) * (HID / 128), 512, 0, stream>>>(
      tokens, wfc1T, fc1_b, NTOK, HID, DIM, h1, nullptr, nullptr, nullptr, nullptr);
  gemm_k<3><<<(NTOK / 256) * (DIM / 128), 512, 0, stream>>>(
      h1, wfc2T, fc2_b, NTOK, DIM, HID, nullptr, outp, nullptr, s1, nullptr);
}

// Round 9
// 520.735 us; speedup vs baseline: 1.0354x; 1.0354x over previous
//
#include <hip/hip_runtime.h>
#include <cstdint>
#include <cstddef>

// SwinBlock3D: LN1 -> roll(-1,-3,-3) -> window(2,7,7) attn (12 heads, rel-bias)
// -> proj + resid -> LN2 -> MLP(384->1536 gelu ->384) + resid.
// bf16 MFMA matmuls; fp32 LN/softmax/final residual; bf16 s1 intermediate.
// GEMM v5 "wave-autonomous": NO barriers. Each wave owns a 64x64 tile:
// A staged to wave-private 8KB LDS (global_load_lds, swizzled), A(kt) in regs
// during MFMA so single-buffer restage is safe; B = packed coalesced fragment
// stream (4 waves/block share one 64-col group -> L1 hits). Latency hidden by
// TLP (3 waves/SIMD, fully desynced), not by intra-block pipelining.

typedef __bf16 bf16x8 __attribute__((ext_vector_type(8)));
typedef __bf16 bf16x4 __attribute__((ext_vector_type(4)));
typedef float f32x4 __attribute__((ext_vector_type(4)));

#define DIM 384
#define QKV_DIM 1152
#define HID 1536
#define NHEADS 12
#define NTOK 50176
#define NWIN 512

// async global->LDS, 16B per lane; LDS dest = wave-uniform base + lane*16
__device__ __forceinline__ void gload16(const void* g, void* s) {
  __builtin_amdgcn_global_load_lds(
      (const __attribute__((address_space(1))) void*)g,
      (__attribute__((address_space(3))) void*)s, 16, 0, 0);
}

// ---------------- prep kernels ----------------
__global__ __launch_bounds__(256) void build_tokmap_k(int* __restrict__ map) {
  int t = blockIdx.x * 256 + threadIdx.x;
  if (t >= NTOK) return;
  int win = t / 98, n = t - win * 98;
  int b = win >> 8, tw = (win >> 6) & 3, hw = (win >> 3) & 7, ww = win & 7;
  int dt = n / 49; int rem = n - dt * 49; int dh = rem / 7, dw = rem - dh * 7;
  int t0 = (tw * 2 + dt + 1) & 7;                 // roll by shift (1,3,3)
  int h0 = hw * 7 + dh + 3; if (h0 >= 56) h0 -= 56;
  int w0 = ww * 7 + dw + 3; if (w0 >= 56) w0 -= 56;
  map[t] = ((b * 8 + t0) * 56 + h0) * 56 + w0;    // spatial row for window-token t
}

// packed bias in MFMA-fragment order: pb[h][mi][ni][lane][r], j>=98 mask pre-baked
__global__ __launch_bounds__(256) void expand_biasp_k(const float* __restrict__ table,
                                                      const int* __restrict__ rel,
                                                      float* __restrict__ out) {
  int e = blockIdx.x * 256 + threadIdx.x;
  if (e >= NHEADS * 49 * 256) return;
  int r = e & 3, l = (e >> 2) & 63;
  int rest = e >> 8;
  int ni = rest % 7, mi = (rest / 7) % 7, h = rest / 49;
  int i = mi * 16 + (l >> 4) * 4 + r;
  int j = ni * 16 + (l & 15);
  float v;
  if (j >= 98) v = -1e30f;          // pad-column mask baked in
  else if (i >= 98) v = 0.f;
  else v = table[rel[i * 98 + j] * NHEADS + h];
  out[e] = v;
}

// Pack W[K][N] -> per-64-col fragment stream:
// elem offset = ((cn*nk + kt)*8 + f)*512 + l*8, f = n*2+kk, holds
// W^T[cn*64 + n*16 + (l&15)][kt*64 + (kk*4 + (l>>4))*8 .. +8].
// In-kernel B-load = wave-uniform base + l*16B -> coalesced 1KB chunks.
__global__ __launch_bounds__(256) void pack_w_k(const float* __restrict__ W,
                                                __bf16* __restrict__ WP,
                                                int K, int N, int nk,
                                                int scaleCols, float scale) {
  int idx = blockIdx.x * 256 + threadIdx.x;
  if (idx >= (K * N) >> 3) return;
  int l = idx & 63, f = (idx >> 6) & 7;
  int rest = idx >> 9, kt = rest % nk, cn = rest / nk;
  int n = f >> 1, kk = f & 1;
  int col = cn * 64 + n * 16 + (l & 15);
  int k0 = kt * 64 + (kk * 4 + (l >> 4)) * 8;
  float sc = (col < scaleCols) ? scale : 1.0f;
  bf16x8 v;
  #pragma unroll
  for (int j = 0; j < 8; ++j)
    v[j] = (__bf16)(W[(size_t)(k0 + j) * N + col] * sc);
  *(bf16x8*)(WP + (size_t)idx * 8) = v;
}

__global__ __launch_bounds__(256) void scale_bias_k(const float* __restrict__ b,
                                                    float* __restrict__ out,
                                                    int n, int scaleCols, float scale) {
  int e = blockIdx.x * 256 + threadIdx.x;
  if (e >= n) return;
  out[e] = b[e] * (e < scaleCols ? scale : 1.0f);
}

// V^T: vt[(win*12+h)*32 + d][tok 0..127] bf16, zeros past tok 97
__global__ __launch_bounds__(384) void vtrans_k(const __bf16* __restrict__ qkv,
                                                __bf16* __restrict__ vt) {
  int win = blockIdx.x, t = threadIdx.x;          // t = h*32+d
  const __bf16* base = qkv + (size_t)win * 98 * QKV_DIM + 768 + t;
  __bf16* orow = vt + ((size_t)win * 384 + t) * 128;
  #pragma unroll
  for (int c = 0; c < 16; ++c) {
    bf16x8 pk;
    #pragma unroll
    for (int e2 = 0; e2 < 8; ++e2) {
      int tok = c * 8 + e2;
      pk[e2] = (tok < 98) ? base[(size_t)tok * QKV_DIM] : (__bf16)0.f;
    }
    *(bf16x8*)(orow + c * 8) = pk;
  }
}

// ---------------- layernorm (1 wave per token row of 384) ----------------
template <typename T>
__global__ __launch_bounds__(256) void ln_k(const T* __restrict__ x,
                                            const float* __restrict__ g,
                                            const float* __restrict__ bta,
                                            __bf16* __restrict__ out,
                                            const int* __restrict__ map) {
  int w = threadIdx.x >> 6, l = threadIdx.x & 63;
  int tok = blockIdx.x * 4 + w;
  int src = map ? map[tok] : tok;
  const T* row = x + (size_t)src * DIM;
  float v[6]; float s = 0.f;
  #pragma unroll
  for (int j = 0; j < 6; ++j) { v[j] = (float)row[l + 64 * j]; s += v[j]; }
  #pragma unroll
  for (int m = 1; m < 64; m <<= 1) s += __shfl_xor(s, m, 64);
  float mu = s * (1.f / DIM);
  float var = 0.f;
  #pragma unroll
  for (int j = 0; j < 6; ++j) { float d = v[j] - mu; var += d * d; }
  #pragma unroll
  for (int m = 1; m < 64; m <<= 1) var += __shfl_xor(var, m, 64);
  float rs = rsqrtf(var * (1.f / DIM) + 1e-5f);
  __bf16* orow = out + (size_t)tok * DIM;
  #pragma unroll
  for (int j = 0; j < 6; ++j) {
    int c = l + 64 * j;
    orow[c] = (__bf16)((v[j] - mu) * rs * g[c] + bta[c]);
  }
}

// ------ wave-autonomous 64x64 bf16 MFMA GEMM, BK=64, 4 indep waves ---------
// Block tile 256M x 64N; wave w owns rows m0+w*64..+64, all 64 cols.
// Per K-tile per wave (no barriers anywhere):
//   LOADB(kt) (8 coalesced reg loads, L1-shared across the block's waves)
//   STAGEA(kt+1) into wave-private LDS (safe: A(kt) already in regs)
//   32 MFMA (compiler waits B)  ->  vmcnt(0)  ->  ds_read A(kt+1) + lgkmcnt(0)
// EPI: 0 = +bias -> bf16   1 = +bias + residf(x fp32), scatter tokmap -> bf16
//      2 = +bias, fast-gelu -> bf16   3 = +bias + residb(bf16) -> fp32
template <int EPI>
__global__ __launch_bounds__(256) void gemm_k(const __bf16* __restrict__ A,
                                              const __bf16* __restrict__ WP,
                                              const float* __restrict__ bias,
                                              int M, int N, int K,
                                              __bf16* __restrict__ outb,
                                              float* __restrict__ outf,
                                              const float* __restrict__ residf,
                                              const __bf16* __restrict__ residb,
                                              const int* __restrict__ tokmap) {
  __shared__ __align__(1024) char lds[32768];     // 4 waves x 8KB private
  const int tid = threadIdx.x;
  const int l = tid & 63, w = tid >> 6;
  const int lr = l & 15, lg = l >> 4;
  const int ntile = N >> 6;
  // bijective XCD swizzle (m204)
  const int nwg = gridDim.x, qd = nwg >> 3, rm = nwg & 7;
  const int xcd = blockIdx.x & 7;
  const int wgid = (xcd < rm ? xcd * (qd + 1) : rm * (qd + 1) + (xcd - rm) * qd)
                   + (blockIdx.x >> 3);
  const int bm = wgid / ntile, bn = wgid - bm * ntile;
  const int m0 = (bm << 8) + (w << 6);            // wave's 64-row stripe
  const int n0 = bn << 6;
  const int nk = K >> 6;
  // A staging: lane l covers row (l>>3) (+8 per sweep), chunk pre-swizzled
  const int sch = (l & 7) ^ ((l >> 3) & 7);
  const __bf16* pa = A + (size_t)(m0 + (l >> 3)) * K + sch * 8;
  char* abuf = lds + (w << 13);                   // wave-private 8KB
  // packed-B base for this col-group (shared by all 4 waves -> L1 hits)
  const __bf16* pB = WP + (size_t)bn * nk * 4096 + l * 8;

#define STAGEA(kt)                                                   \
  {                                                                  \
    const size_t ko_ = (size_t)(kt) << 6;                            \
    _Pragma("unroll")                                                \
    for (int s_ = 0; s_ < 8; ++s_)                                   \
      gload16(pa + (size_t)(s_ * 8) * K + ko_, abuf + s_ * 1024);    \
  }
#define LOADB(kt)                                                    \
  {                                                                  \
    const __bf16* p_ = pB + (size_t)(kt) * 4096;                     \
    _Pragma("unroll")                                                \
    for (int f_ = 0; f_ < 8; ++f_)                                   \
      b[f_] = *(const bf16x8*)(p_ + f_ * 512);                       \
  }
#define LDA()                                                        \
  {                                                                  \
    _Pragma("unroll")                                                \
    for (int kk_ = 0; kk_ < 2; ++kk_) {                              \
      const int ck_ = (kk_ << 2) + lg;                               \
      _Pragma("unroll")                                              \
      for (int m_ = 0; m_ < 4; ++m_) {                               \
        int r_ = (m_ << 4) + lr;                                     \
        a[m_][kk_] = *(const bf16x8*)(abuf + (r_ << 7) +             \
                                      ((ck_ ^ (r_ & 7)) << 4));      \
      }                                                              \
    }                                                                \
    asm volatile("s_waitcnt lgkmcnt(0)" ::: "memory");               \
    __builtin_amdgcn_sched_barrier(0);                               \
  }

  bf16x8 a[4][2], b[8];
  f32x4 acc[4][4] = {};

  // prologue: A(0) -> LDS -> regs (wave-private waits only)
  STAGEA(0)
  asm volatile("s_waitcnt vmcnt(0)" ::: "memory");
  LDA()

  for (int kt = 0; kt < nk; ++kt) {
    LOADB(kt)                         // B(kt) -> regs (oldest VMEM this iter)
    const bool pf = (kt + 1 < nk);
    if (pf) STAGEA(kt + 1)            // overwrite OK: A(kt) lives in a[][]
    __builtin_amdgcn_s_setprio(1);
    #pragma unroll
    for (int kk = 0; kk < 2; ++kk)
      #pragma unroll
      for (int m = 0; m < 4; ++m)
        #pragma unroll
        for (int n = 0; n < 4; ++n)   // swapped operands -> C^T fragment layout
          acc[m][n] = __builtin_amdgcn_mfma_f32_16x16x32_bf16(b[n * 2 + kk], a[m][kk],
                                                              acc[m][n], 0, 0, 0);
    __builtin_amdgcn_s_setprio(0);
    if (pf) {
      asm volatile("s_waitcnt vmcnt(0)" ::: "memory");   // A(kt+1) DMA landed
      LDA()
    }
  }
#undef STAGEA
#undef LOADB
#undef LDA

  // epilogue (C^T frags): row = m0+m*16+lr, cols = n0+n*16+lg*4..+3
  #pragma unroll
  for (int m = 0; m < 4; ++m) {
    const int grow = m0 + (m << 4) + lr;
    #pragma unroll
    for (int n = 0; n < 4; ++n) {
      const int gcol = n0 + (n << 4) + (lg << 2);
      f32x4 a4 = acc[m][n] + *(const f32x4*)(bias + gcol);
      if (EPI == 0) {
        bf16x4 c;
        #pragma unroll
        for (int r = 0; r < 4; ++r) c[r] = (__bf16)a4[r];
        *(bf16x4*)(outb + (size_t)grow * N + gcol) = c;
      } else if (EPI == 1) {
        int dst = tokmap[grow];
        f32x4 rv = *(const f32x4*)(residf + (size_t)dst * DIM + gcol);
        bf16x4 c;
        #pragma unroll
        for (int r = 0; r < 4; ++r) c[r] = (__bf16)(rv[r] + a4[r]);
        *(bf16x4*)(outb + (size_t)dst * DIM + gcol) = c;
      } else if (EPI == 2) {
        bf16x4 c;
        #pragma unroll
        for (int r = 0; r < 4; ++r) {
          float vv = a4[r];
          float y = vv * (1.0f + 0.044715f * vv * vv);
          c[r] = (__bf16)(vv / (1.0f + __expf(-1.5957691216057308f * y)));
        }
        *(bf16x4*)(outb + (size_t)grow * N + gcol) = c;
      } else {
        bf16x4 sv = *(const bf16x4*)(residb + (size_t)grow * N + gcol);
        f32x4 o;
        #pragma unroll
        for (int r = 0; r < 4; ++r) o[r] = (float)sv[r] + a4[r];
        *(f32x4*)(outf + (size_t)grow * N + gcol) = o;
      }
    }
  }
}

// ---------------- window attention: 1 wave per (window, head, mi-tile) ------
__global__ __launch_bounds__(64) void attn_k(const __bf16* __restrict__ qkv,
                                             const __bf16* __restrict__ vt,
                                             const float* __restrict__ pb,
                                             __bf16* __restrict__ out) {
  __shared__ __align__(1024) char P[4096];
  const int l = threadIdx.x, lr = l & 15, lg = l >> 4;
  const int bid = blockIdx.x;
  const int xc = bid & 7, kk = bid >> 3;
  const int wh = (kk / 7) * 8 + xc, mi = kk % 7;
  const int win = wh / NHEADS, h = wh - win * NHEADS;
  const size_t wbase = (size_t)win * 98 * QKV_DIM;
  const __bf16* qb = qkv + wbase + h * 32;
  const __bf16* kb = qb + 384;
  const bf16x8 z8 = {};
  const f32x4 fz = {};

  bf16x8 kf[7];
  #pragma unroll
  for (int ni = 0; ni < 7; ++ni) {
    int tok = ni * 16 + lr;
    kf[ni] = (tok < 98) ? *(const bf16x8*)(kb + (size_t)tok * QKV_DIM + lg * 8) : z8;
  }
  int qt = mi * 16 + lr;
  bf16x8 qf = (qt < 98) ? *(const bf16x8*)(qb + (size_t)qt * QKV_DIM + lg * 8) : z8;
  const f32x4* pbp = (const f32x4*)pb + (size_t)((h * 7 + mi) * 7) * 64 + l;
  f32x4 bv[7];
  #pragma unroll
  for (int ni = 0; ni < 7; ++ni) bv[ni] = pbp[ni * 64];

  f32x4 s[7];
  #pragma unroll
  for (int ni = 0; ni < 7; ++ni)
    s[ni] = __builtin_amdgcn_mfma_f32_16x16x32_bf16(qf, kf[ni], fz, 0, 0, 0);

  if (l < 32) {
    int row = l >> 1, c = 14 + (l & 1);
    *(f32x4*)(P + row * 256 + ((c ^ (row & 7)) << 4)) = fz;
  }

  #pragma unroll
  for (int r = 0; r < 4; ++r) {
    float mx = -1e30f;
    #pragma unroll
    for (int ni = 0; ni < 7; ++ni) {
      float vv = s[ni][r] + bv[ni][r];
      s[ni][r] = vv;
      mx = fmaxf(mx, vv);
    }
    #pragma unroll
    for (int m2 = 1; m2 < 16; m2 <<= 1) mx = fmaxf(mx, __shfl_xor(mx, m2, 64));
    float sum = 0.f;
    #pragma unroll
    for (int ni = 0; ni < 7; ++ni) { float p = __expf(s[ni][r] - mx); s[ni][r] = p; sum += p; }
    #pragma unroll
    for (int m2 = 1; m2 < 16; m2 <<= 1) sum += __shfl_xor(sum, m2, 64);
    float inv = 1.0f / sum;
    int il = lg * 4 + r;
    #pragma unroll
    for (int ni = 0; ni < 7; ++ni) {
      int j = ni * 16 + lr;
      *(__bf16*)(P + il * 256 + (((j >> 3) ^ (il & 7)) << 4) + ((j & 7) << 1)) =
          (__bf16)(s[ni][r] * inv);
    }
  }
  __syncthreads();

  bf16x8 pa[4];
  #pragma unroll
  for (int ks = 0; ks < 4; ++ks) {
    int ck = ks * 4 + lg;
    pa[ks] = *(const bf16x8*)(P + lr * 256 + ((ck ^ (lr & 7)) << 4));
  }
  const __bf16* vrow = vt + ((size_t)wh * 32) * 128;
  __bf16* ob = out + ((size_t)win * 98 + mi * 16) * DIM + h * 32;
  #pragma unroll
  for (int nf = 0; nf < 2; ++nf) {
    int d = nf * 16 + lr;
    f32x4 o = fz;
    #pragma unroll
    for (int ks = 0; ks < 4; ++ks) {
      bf16x8 vb = *(const bf16x8*)(vrow + (size_t)d * 128 + ks * 32 + lg * 8);
      o = __builtin_amdgcn_mfma_f32_16x16x32_bf16(pa[ks], vb, o, 0, 0, 0);
    }
    #pragma unroll
    for (int r = 0; r < 4; ++r) {
      int il = lg * 4 + r;
      if (mi * 16 + il < 98) ob[(size_t)il * DIM + nf * 16 + lr] = (__bf16)o[r];
    }
  }
}

// ---------------- launch ----------------
extern "C" void kernel_launch(void* const* d_in, const int* in_sizes, int n_in,
                              void* d_out, int out_size, void* d_ws, size_t ws_size,
                              hipStream_t stream) {
  const float* x      = (const float*)d_in[0];
  const float* n1g    = (const float*)d_in[1];
  const float* n1b    = (const float*)d_in[2];
  const float* qkv_w  = (const float*)d_in[3];
  const float* qkv_b  = (const float*)d_in[4];
  const float* proj_w = (const float*)d_in[5];
  const float* proj_b = (const float*)d_in[6];
  const float* btab   = (const float*)d_in[7];
  const float* n2g    = (const float*)d_in[8];
  const float* n2b    = (const float*)d_in[9];
  const float* fc1_w  = (const float*)d_in[10];
  const float* fc1_b  = (const float*)d_in[11];
  const float* fc2_w  = (const float*)d_in[12];
  const float* fc2_b  = (const float*)d_in[13];
  const int*   relidx = (const int*)d_in[14];
  float* outp = (float*)d_out;
  (void)in_sizes; (void)n_in; (void)out_size; (void)ws_size;

  char* ws = (char*)d_ws;
  size_t off = 0;
  auto alloc = [&](size_t bytes) {
    char* p = ws + off;
    off = (off + bytes + 255) & ~(size_t)255;
    return p;
  };
  int*    tokmap = (int*)alloc((size_t)NTOK * 4);
  float*  biasex = (float*)alloc((size_t)NHEADS * 49 * 256 * 4);
  __bf16* wqkvP  = (__bf16*)alloc((size_t)QKV_DIM * DIM * 2);
  __bf16* wprojP = (__bf16*)alloc((size_t)DIM * DIM * 2);
  __bf16* wfc1P  = (__bf16*)alloc((size_t)HID * DIM * 2);
  __bf16* wfc2P  = (__bf16*)alloc((size_t)DIM * HID * 2);
  float*  qkvbS  = (float*)alloc((size_t)QKV_DIM * 4);
  __bf16* tokens = (__bf16*)alloc((size_t)NTOK * DIM * 2);   // LN1 out / attn out / LN2 out
  __bf16* qkvbuf = (__bf16*)alloc((size_t)NTOK * HID * 2);   // qkv (1152) then h1 (1536)
  __bf16* s1     = (__bf16*)alloc((size_t)NTOK * DIM * 2);   // x + attn-proj, bf16
  __bf16* attnout = tokens;
  __bf16* h1 = qkvbuf;
  // vt (50.3MB) lives in d_out (77MB fp32) — only fc2 writes d_out, at the end
  __bf16* vt = (__bf16*)d_out;

  const float scale = 0.17677669529663687f;  // 1/sqrt(32)

  build_tokmap_k<<<NTOK / 256, 256, 0, stream>>>(tokmap);
  expand_biasp_k<<<(NHEADS * 49 * 256) / 256, 256, 0, stream>>>(btab, relidx, biasex);
  pack_w_k<<<(DIM * QKV_DIM / 8) / 256, 256, 0, stream>>>(qkv_w, wqkvP, DIM, QKV_DIM, 6, DIM, scale);
  pack_w_k<<<(DIM * DIM / 8) / 256, 256, 0, stream>>>(proj_w, wprojP, DIM, DIM, 6, 0, 1.0f);
  pack_w_k<<<(DIM * HID / 8) / 256, 256, 0, stream>>>(fc1_w, wfc1P, DIM, HID, 6, 0, 1.0f);
  pack_w_k<<<(HID * DIM / 8) / 256, 256, 0, stream>>>(fc2_w, wfc2P, HID, DIM, 24, 0, 1.0f);
  scale_bias_k<<<(QKV_DIM + 255) / 256, 256, 0, stream>>>(qkv_b, qkvbS, QKV_DIM, DIM, scale);

  ln_k<float><<<NTOK / 4, 256, 0, stream>>>(x, n1g, n1b, tokens, tokmap);
  gemm_k<0><<<(NTOK / 256) * (QKV_DIM / 64), 256, 0, stream>>>(
      tokens, wqkvP, qkvbS, NTOK, QKV_DIM, DIM, qkvbuf, nullptr, nullptr, nullptr, nullptr);
  vtrans_k<<<NWIN, 384, 0, stream>>>(qkvbuf, vt);
  attn_k<<<NWIN * NHEADS * 7, 64, 0, stream>>>(qkvbuf, vt, biasex, attnout);
  gemm_k<1><<<(NTOK / 256) * (DIM / 64), 256, 0, stream>>>(
      attnout, wprojP, proj_b, NTOK, DIM, DIM, s1, nullptr, x, nullptr, tokmap);
  ln_k<__bf16><<<NTOK / 4, 256, 0, stream>>>(s1, n2g, n2b, tokens, nullptr);
  gemm_k<2><<<(NTOK / 256) * (HID / 64), 256, 0, stream>>>(
      tokens, wfc1P, fc1_b, NTOK, HID, DIM, h1, nullptr, nullptr, nullptr, nullptr);
  gemm_k<3><<<(NTOK / 256) * (DIM / 64), 256, 0, stream>>>(
      h1, wfc2P, fc2_b, NTOK, DIM, HID, nullptr, outp, nullptr, s1, nullptr);
}

// Round 10
// 489.581 us; speedup vs baseline: 1.1013x; 1.0636x over previous
//
#include <hip/hip_runtime.h>
#include <cstdint>
#include <cstddef>

// SwinBlock3D: LN1 -> roll(-1,-3,-3) -> window(2,7,7) attn (12 heads, rel-bias)
// -> proj + resid -> LN2 -> MLP(384->1536 gelu ->384) + resid.
// bf16 MFMA matmuls; fp32 LN/softmax/final residual; bf16 s1 intermediate.
// R10: every global STORE is wave-contiguous via LDS transpose. R9 diagnosis:
// all GEMM variants were capped by scattered 8B/lane epilogue stores
// (dur ~= WRITE_SIZE / 1.05 TB/s across R4-R9); ln_k's contiguous stores
// stream at ~5 TB/s on the same chip.

typedef __bf16 bf16x8 __attribute__((ext_vector_type(8)));
typedef __bf16 bf16x4 __attribute__((ext_vector_type(4)));
typedef float f32x4 __attribute__((ext_vector_type(4)));

#define DIM 384
#define QKV_DIM 1152
#define HID 1536
#define NHEADS 12
#define NTOK 50176
#define NWIN 512

// async global->LDS, 16B per lane; LDS dest = wave-uniform base + lane*16
__device__ __forceinline__ void gload16(const void* g, void* s) {
  __builtin_amdgcn_global_load_lds(
      (const __attribute__((address_space(1))) void*)g,
      (__attribute__((address_space(3))) void*)s, 16, 0, 0);
}

// ---------------- prep kernels ----------------
__global__ __launch_bounds__(256) void build_tokmap_k(int* __restrict__ map) {
  int t = blockIdx.x * 256 + threadIdx.x;
  if (t >= NTOK) return;
  int win = t / 98, n = t - win * 98;
  int b = win >> 8, tw = (win >> 6) & 3, hw = (win >> 3) & 7, ww = win & 7;
  int dt = n / 49; int rem = n - dt * 49; int dh = rem / 7, dw = rem - dh * 7;
  int t0 = (tw * 2 + dt + 1) & 7;                 // roll by shift (1,3,3)
  int h0 = hw * 7 + dh + 3; if (h0 >= 56) h0 -= 56;
  int w0 = ww * 7 + dw + 3; if (w0 >= 56) w0 -= 56;
  map[t] = ((b * 8 + t0) * 56 + h0) * 56 + w0;    // spatial row for window-token t
}

// packed bias in MFMA-fragment order: pb[h][mi][ni][lane][r], j>=98 mask pre-baked
__global__ __launch_bounds__(256) void expand_biasp_k(const float* __restrict__ table,
                                                      const int* __restrict__ rel,
                                                      float* __restrict__ out) {
  int e = blockIdx.x * 256 + threadIdx.x;
  if (e >= NHEADS * 49 * 256) return;
  int r = e & 3, l = (e >> 2) & 63;
  int rest = e >> 8;
  int ni = rest % 7, mi = (rest / 7) % 7, h = rest / 49;
  int i = mi * 16 + (l >> 4) * 4 + r;
  int j = ni * 16 + (l & 15);
  float v;
  if (j >= 98) v = -1e30f;          // pad-column mask baked in
  else if (i >= 98) v = 0.f;
  else v = table[rel[i * 98 + j] * NHEADS + h];
  out[e] = v;
}

// Pack W[K][N] -> per-64-col fragment stream (proven coalesced B path, R7)
__global__ __launch_bounds__(256) void pack_w_k(const float* __restrict__ W,
                                                __bf16* __restrict__ WP,
                                                int K, int N, int nk,
                                                int scaleCols, float scale) {
  int idx = blockIdx.x * 256 + threadIdx.x;
  if (idx >= (K * N) >> 3) return;
  int l = idx & 63, f = (idx >> 6) & 7;
  int rest = idx >> 9, kt = rest % nk, cn = rest / nk;
  int n = f >> 1, kk = f & 1;
  int col = cn * 64 + n * 16 + (l & 15);
  int k0 = kt * 64 + (kk * 4 + (l >> 4)) * 8;
  float sc = (col < scaleCols) ? scale : 1.0f;
  bf16x8 v;
  #pragma unroll
  for (int j = 0; j < 8; ++j)
    v[j] = (__bf16)(W[(size_t)(k0 + j) * N + col] * sc);
  *(bf16x8*)(WP + (size_t)idx * 8) = v;
}

__global__ __launch_bounds__(256) void scale_bias_k(const float* __restrict__ b,
                                                    float* __restrict__ out,
                                                    int n, int scaleCols, float scale) {
  int e = blockIdx.x * 256 + threadIdx.x;
  if (e >= n) return;
  out[e] = b[e] * (e < scaleCols ? scale : 1.0f);
}

// V^T via LDS transpose: coalesced reads (lane=d contiguous) AND coalesced
// 16B/lane linear stores (was 64x 16B scattered segments per instr).
__global__ __launch_bounds__(384) void vtrans_k(const __bf16* __restrict__ qkv,
                                                __bf16* __restrict__ vt) {
  __shared__ __align__(1024) char T[98304];       // 384 rows x 256B
  int win = blockIdx.x, t = threadIdx.x;          // t = h*32+d
  const __bf16* base = qkv + (size_t)win * 98 * QKV_DIM + 768 + t;
  #pragma unroll
  for (int c = 0; c < 16; ++c) {
    bf16x8 pk;
    #pragma unroll
    for (int e2 = 0; e2 < 8; ++e2) {
      int tok = c * 8 + e2;
      pk[e2] = (tok < 98) ? base[(size_t)tok * QKV_DIM] : (__bf16)0.f;
    }
    *(bf16x8*)(T + t * 256 + ((c ^ (t & 15)) << 4)) = pk;   // swizzled row
  }
  __syncthreads();
  char* wb = (char*)(vt + (size_t)win * 49152);   // 96KB block, contiguous
  #pragma unroll
  for (int i = 0; i < 16; ++i) {
    int g = i * 6144 + t * 16;
    int row = g >> 8, p = (g >> 4) & 15;
    bf16x8 v = *(const bf16x8*)(T + row * 256 + (p << 4));
    int lc = p ^ (row & 15);                      // unswizzle -> logical chunk
    *(bf16x8*)(wb + row * 256 + (lc << 4)) = v;   // 256B-contig segments
  }
}

// ---------------- layernorm (1 wave per token row of 384) ----------------
template <typename T>
__global__ __launch_bounds__(256) void ln_k(const T* __restrict__ x,
                                            const float* __restrict__ g,
                                            const float* __restrict__ bta,
                                            __bf16* __restrict__ out,
                                            const int* __restrict__ map) {
  int w = threadIdx.x >> 6, l = threadIdx.x & 63;
  int tok = blockIdx.x * 4 + w;
  int src = map ? map[tok] : tok;
  const T* row = x + (size_t)src * DIM;
  float v[6]; float s = 0.f;
  #pragma unroll
  for (int j = 0; j < 6; ++j) { v[j] = (float)row[l + 64 * j]; s += v[j]; }
  #pragma unroll
  for (int m = 1; m < 64; m <<= 1) s += __shfl_xor(s, m, 64);
  float mu = s * (1.f / DIM);
  float var = 0.f;
  #pragma unroll
  for (int j = 0; j < 6; ++j) { float d = v[j] - mu; var += d * d; }
  #pragma unroll
  for (int m = 1; m < 64; m <<= 1) var += __shfl_xor(var, m, 64);
  float rs = rsqrtf(var * (1.f / DIM) + 1e-5f);
  __bf16* orow = out + (size_t)tok * DIM;
  #pragma unroll
  for (int j = 0; j < 6; ++j) {
    int c = l + 64 * j;
    orow[c] = (__bf16)((v[j] - mu) * rs * g[c] + bta[c]);
  }
}

// ------ wave-autonomous 64x64 bf16 MFMA GEMM, BK=64 (R9 loop) + coalesced
// LDS-transposed epilogue: stage C-tile in abuf (free after K-loop), read back
// row-contiguous, store 8 full 128B rows per instruction.
// EPI: 0 = +bias -> bf16   1 = +bias + residf(x fp32), scatter tokmap -> bf16
//      2 = +bias, fast-gelu -> bf16   3 = +bias + residb(bf16) -> fp32
template <int EPI>
__global__ __launch_bounds__(256) void gemm_k(const __bf16* __restrict__ A,
                                              const __bf16* __restrict__ WP,
                                              const float* __restrict__ bias,
                                              int M, int N, int K,
                                              __bf16* __restrict__ outb,
                                              float* __restrict__ outf,
                                              const float* __restrict__ residf,
                                              const __bf16* __restrict__ residb,
                                              const int* __restrict__ tokmap) {
  __shared__ __align__(1024) char lds[32768];     // 4 waves x 8KB private
  const int tid = threadIdx.x;
  const int l = tid & 63, w = tid >> 6;
  const int lr = l & 15, lg = l >> 4;
  const int ntile = N >> 6;
  // bijective XCD swizzle (m204)
  const int nwg = gridDim.x, qd = nwg >> 3, rm = nwg & 7;
  const int xcd = blockIdx.x & 7;
  const int wgid = (xcd < rm ? xcd * (qd + 1) : rm * (qd + 1) + (xcd - rm) * qd)
                   + (blockIdx.x >> 3);
  const int bm = wgid / ntile, bn = wgid - bm * ntile;
  const int m0 = (bm << 8) + (w << 6);            // wave's 64-row stripe
  const int n0 = bn << 6;
  const int nk = K >> 6;
  const int sch = (l & 7) ^ ((l >> 3) & 7);
  const __bf16* pa = A + (size_t)(m0 + (l >> 3)) * K + sch * 8;
  char* abuf = lds + (w << 13);                   // wave-private 8KB
  const __bf16* pB = WP + (size_t)bn * nk * 4096 + l * 8;

#define STAGEA(kt)                                                   \
  {                                                                  \
    const size_t ko_ = (size_t)(kt) << 6;                            \
    _Pragma("unroll")                                                \
    for (int s_ = 0; s_ < 8; ++s_)                                   \
      gload16(pa + (size_t)(s_ * 8) * K + ko_, abuf + s_ * 1024);    \
  }
#define LOADB(kt)                                                    \
  {                                                                  \
    const __bf16* p_ = pB + (size_t)(kt) * 4096;                     \
    _Pragma("unroll")                                                \
    for (int f_ = 0; f_ < 8; ++f_)                                   \
      b[f_] = *(const bf16x8*)(p_ + f_ * 512);                       \
  }
#define LDA()                                                        \
  {                                                                  \
    _Pragma("unroll")                                                \
    for (int kk_ = 0; kk_ < 2; ++kk_) {                              \
      const int ck_ = (kk_ << 2) + lg;                               \
      _Pragma("unroll")                                              \
      for (int m_ = 0; m_ < 4; ++m_) {                               \
        int r_ = (m_ << 4) + lr;                                     \
        a[m_][kk_] = *(const bf16x8*)(abuf + (r_ << 7) +             \
                                      ((ck_ ^ (r_ & 7)) << 4));      \
      }                                                              \
    }                                                                \
    asm volatile("s_waitcnt lgkmcnt(0)" ::: "memory");               \
    __builtin_amdgcn_sched_barrier(0);                               \
  }

  bf16x8 a[4][2], b[8];
  f32x4 acc[4][4] = {};

  STAGEA(0)
  asm volatile("s_waitcnt vmcnt(0)" ::: "memory");
  LDA()

  for (int kt = 0; kt < nk; ++kt) {
    LOADB(kt)
    const bool pf = (kt + 1 < nk);
    if (pf) STAGEA(kt + 1)            // overwrite OK: A(kt) lives in a[][]
    __builtin_amdgcn_s_setprio(1);
    #pragma unroll
    for (int kk = 0; kk < 2; ++kk)
      #pragma unroll
      for (int m = 0; m < 4; ++m)
        #pragma unroll
        for (int n = 0; n < 4; ++n)   // swapped operands -> C^T fragment layout
          acc[m][n] = __builtin_amdgcn_mfma_f32_16x16x32_bf16(b[n * 2 + kk], a[m][kk],
                                                              acc[m][n], 0, 0, 0);
    __builtin_amdgcn_s_setprio(0);
    if (pf) {
      asm volatile("s_waitcnt vmcnt(0)" ::: "memory");
      LDA()
    }
  }
#undef STAGEA
#undef LOADB
#undef LDA

  // ---- coalesced epilogue via LDS transpose (abuf free; DS is in-order) ----
  if (EPI == 3) {
    // fp32 out: two 64x32 half-tiles (8KB each)
    #pragma unroll
    for (int hh = 0; hh < 2; ++hh) {
      #pragma unroll
      for (int m = 0; m < 4; ++m) {
        const int row = (m << 4) + lr;
        #pragma unroll
        for (int n2 = 0; n2 < 2; ++n2) {
          const int n = (hh << 1) + n2;
          const int gcol = n0 + (n << 4) + (lg << 2);
          f32x4 a4 = acc[m][n] + *(const f32x4*)(bias + gcol);
          const int ch = (n2 << 2) + lg;
          *(f32x4*)(abuf + (row << 7) + ((ch ^ (row & 7)) << 4)) = a4;
        }
      }
      asm volatile("s_waitcnt lgkmcnt(0)" ::: "memory");
      __builtin_amdgcn_sched_barrier(0);
      #pragma unroll
      for (int i = 0; i < 8; ++i) {
        const int row = (i << 3) + (l >> 3);
        const int p = (l & 7) ^ (row & 7);        // phys chunk for logical l&7
        f32x4 v = *(const f32x4*)(abuf + (row << 7) + (p << 4));
        const int grow = m0 + row;
        const int gcol = n0 + (hh << 5) + ((l & 7) << 2);
        bf16x4 sv = *(const bf16x4*)(residb + (size_t)grow * N + gcol);
        f32x4 o;
        #pragma unroll
        for (int r = 0; r < 4; ++r) o[r] = v[r] + (float)sv[r];
        *(f32x4*)(outf + (size_t)grow * N + gcol) = o;  // 8 lanes = 128B/row
      }
      if (hh == 0) {
        asm volatile("s_waitcnt lgkmcnt(0)" ::: "memory");
        __builtin_amdgcn_sched_barrier(0);
      }
    }
  } else {
    // bf16 out: 64x64 tile (8KB)
    #pragma unroll
    for (int m = 0; m < 4; ++m) {
      const int row = (m << 4) + lr;
      #pragma unroll
      for (int n = 0; n < 4; ++n) {
        const int gcol = n0 + (n << 4) + (lg << 2);
        f32x4 a4 = acc[m][n] + *(const f32x4*)(bias + gcol);
        bf16x4 c;
        if (EPI == 2) {
          #pragma unroll
          for (int r = 0; r < 4; ++r) {
            float vv = a4[r];
            float y = vv * (1.0f + 0.044715f * vv * vv);
            c[r] = (__bf16)(vv / (1.0f + __expf(-1.5957691216057308f * y)));
          }
        } else {
          #pragma unroll
          for (int r = 0; r < 4; ++r) c[r] = (__bf16)a4[r];
        }
        const int ch = (n << 1) + (lg >> 1);
        *(bf16x4*)(abuf + (row << 7) + ((ch ^ (row & 7)) << 4) + ((lg & 1) << 3)) = c;
      }
    }
    asm volatile("s_waitcnt lgkmcnt(0)" ::: "memory");
    __builtin_amdgcn_sched_barrier(0);
    #pragma unroll
    for (int i = 0; i < 8; ++i) {
      const int row = (i << 3) + (l >> 3);
      const int p = (l & 7) ^ (row & 7);
      bf16x8 v = *(const bf16x8*)(abuf + (row << 7) + (p << 4));
      const int gcol = n0 + ((l & 7) << 3);
      if (EPI == 1) {
        const int dst = tokmap[m0 + row];
        const float* rp = residf + (size_t)dst * N + gcol;
        f32x4 r0 = *(const f32x4*)rp, r1 = *(const f32x4*)(rp + 4);
        bf16x8 c2;
        #pragma unroll
        for (int j = 0; j < 4; ++j) {
          c2[j] = (__bf16)(r0[j] + (float)v[j]);
          c2[j + 4] = (__bf16)(r1[j] + (float)v[j + 4]);
        }
        *(bf16x8*)(outb + (size_t)dst * N + gcol) = c2;
      } else {
        *(bf16x8*)(outb + (size_t)(m0 + row) * N + gcol) = v;  // 8 rows x 128B
      }
    }
  }
}

// ---------------- window attention: 1 wave per (window, head, mi-tile) ------
__global__ __launch_bounds__(64) void attn_k(const __bf16* __restrict__ qkv,
                                             const __bf16* __restrict__ vt,
                                             const float* __restrict__ pb,
                                             __bf16* __restrict__ out) {
  __shared__ __align__(1024) char P[4096];
  const int l = threadIdx.x, lr = l & 15, lg = l >> 4;
  const int bid = blockIdx.x;
  const int xc = bid & 7, kk = bid >> 3;
  const int wh = (kk / 7) * 8 + xc, mi = kk % 7;
  const int win = wh / NHEADS, h = wh - win * NHEADS;
  const size_t wbase = (size_t)win * 98 * QKV_DIM;
  const __bf16* qb = qkv + wbase + h * 32;
  const __bf16* kb = qb + 384;
  const bf16x8 z8 = {};
  const f32x4 fz = {};

  bf16x8 kf[7];
  #pragma unroll
  for (int ni = 0; ni < 7; ++ni) {
    int tok = ni * 16 + lr;
    kf[ni] = (tok < 98) ? *(const bf16x8*)(kb + (size_t)tok * QKV_DIM + lg * 8) : z8;
  }
  int qt = mi * 16 + lr;
  bf16x8 qf = (qt < 98) ? *(const bf16x8*)(qb + (size_t)qt * QKV_DIM + lg * 8) : z8;
  const f32x4* pbp = (const f32x4*)pb + (size_t)((h * 7 + mi) * 7) * 64 + l;
  f32x4 bv[7];
  #pragma unroll
  for (int ni = 0; ni < 7; ++ni) bv[ni] = pbp[ni * 64];

  f32x4 s[7];
  #pragma unroll
  for (int ni = 0; ni < 7; ++ni)
    s[ni] = __builtin_amdgcn_mfma_f32_16x16x32_bf16(qf, kf[ni], fz, 0, 0, 0);

  if (l < 32) {
    int row = l >> 1, c = 14 + (l & 1);
    *(f32x4*)(P + row * 256 + ((c ^ (row & 7)) << 4)) = fz;
  }

  #pragma unroll
  for (int r = 0; r < 4; ++r) {
    float mx = -1e30f;
    #pragma unroll
    for (int ni = 0; ni < 7; ++ni) {
      float vv = s[ni][r] + bv[ni][r];
      s[ni][r] = vv;
      mx = fmaxf(mx, vv);
    }
    #pragma unroll
    for (int m2 = 1; m2 < 16; m2 <<= 1) mx = fmaxf(mx, __shfl_xor(mx, m2, 64));
    float sum = 0.f;
    #pragma unroll
    for (int ni = 0; ni < 7; ++ni) { float p = __expf(s[ni][r] - mx); s[ni][r] = p; sum += p; }
    #pragma unroll
    for (int m2 = 1; m2 < 16; m2 <<= 1) sum += __shfl_xor(sum, m2, 64);
    float inv = 1.0f / sum;
    int il = lg * 4 + r;
    #pragma unroll
    for (int ni = 0; ni < 7; ++ni) {
      int j = ni * 16 + lr;
      *(__bf16*)(P + il * 256 + (((j >> 3) ^ (il & 7)) << 4) + ((j & 7) << 1)) =
          (__bf16)(s[ni][r] * inv);
    }
  }
  __syncthreads();

  bf16x8 pa[4];
  #pragma unroll
  for (int ks = 0; ks < 4; ++ks) {
    int ck = ks * 4 + lg;
    pa[ks] = *(const bf16x8*)(P + lr * 256 + ((ck ^ (lr & 7)) << 4));
  }
  const __bf16* vrow = vt + ((size_t)wh * 32) * 128;
  f32x4 oo[2];
  #pragma unroll
  for (int nf = 0; nf < 2; ++nf) {
    int d = nf * 16 + lr;
    f32x4 o = fz;
    #pragma unroll
    for (int ks = 0; ks < 4; ++ks) {
      bf16x8 vb = *(const bf16x8*)(vrow + (size_t)d * 128 + ks * 32 + lg * 8);
      o = __builtin_amdgcn_mfma_f32_16x16x32_bf16(pa[ks], vb, o, 0, 0, 0);
    }
    oo[nf] = o;
  }
  // stage 16x32 PV tile to P (pa already consumed), one coalesced store pass
  #pragma unroll
  for (int nf = 0; nf < 2; ++nf)
    #pragma unroll
    for (int r = 0; r < 4; ++r)
      *(__bf16*)(P + (lg * 4 + r) * 64 + (((nf << 4) + lr) << 1)) = (__bf16)oo[nf][r];
  asm volatile("s_waitcnt lgkmcnt(0)" ::: "memory");
  __builtin_amdgcn_sched_barrier(0);
  {
    const int row = l >> 2;
    bf16x8 v = *(const bf16x8*)(P + row * 64 + ((l & 3) << 4));
    const int tok = mi * 16 + row;
    if (tok < 98)
      *(bf16x8*)(out + ((size_t)win * 98 + tok) * DIM + h * 32 + ((l & 3) << 3)) = v;
  }
}

// ---------------- launch ----------------
extern "C" void kernel_launch(void* const* d_in, const int* in_sizes, int n_in,
                              void* d_out, int out_size, void* d_ws, size_t ws_size,
                              hipStream_t stream) {
  const float* x      = (const float*)d_in[0];
  const float* n1g    = (const float*)d_in[1];
  const float* n1b    = (const float*)d_in[2];
  const float* qkv_w  = (const float*)d_in[3];
  const float* qkv_b  = (const float*)d_in[4];
  const float* proj_w = (const float*)d_in[5];
  const float* proj_b = (const float*)d_in[6];
  const float* btab   = (const float*)d_in[7];
  const float* n2g    = (const float*)d_in[8];
  const float* n2b    = (const float*)d_in[9];
  const float* fc1_w  = (const float*)d_in[10];
  const float* fc1_b  = (const float*)d_in[11];
  const float* fc2_w  = (const float*)d_in[12];
  const float* fc2_b  = (const float*)d_in[13];
  const int*   relidx = (const int*)d_in[14];
  float* outp = (float*)d_out;
  (void)in_sizes; (void)n_in; (void)out_size; (void)ws_size;

  char* ws = (char*)d_ws;
  size_t off = 0;
  auto alloc = [&](size_t bytes) {
    char* p = ws + off;
    off = (off + bytes + 255) & ~(size_t)255;
    return p;
  };
  int*    tokmap = (int*)alloc((size_t)NTOK * 4);
  float*  biasex = (float*)alloc((size_t)NHEADS * 49 * 256 * 4);
  __bf16* wqkvP  = (__bf16*)alloc((size_t)QKV_DIM * DIM * 2);
  __bf16* wprojP = (__bf16*)alloc((size_t)DIM * DIM * 2);
  __bf16* wfc1P  = (__bf16*)alloc((size_t)HID * DIM * 2);
  __bf16* wfc2P  = (__bf16*)alloc((size_t)DIM * HID * 2);
  float*  qkvbS  = (float*)alloc((size_t)QKV_DIM * 4);
  __bf16* tokens = (__bf16*)alloc((size_t)NTOK * DIM * 2);   // LN1 out / attn out / LN2 out
  __bf16* qkvbuf = (__bf16*)alloc((size_t)NTOK * HID * 2);   // qkv (1152) then h1 (1536)
  __bf16* s1     = (__bf16*)alloc((size_t)NTOK * DIM * 2);   // x + attn-proj, bf16
  __bf16* attnout = tokens;
  __bf16* h1 = qkvbuf;
  // vt (50.3MB) lives in d_out (77MB fp32) — only fc2 writes d_out, at the end
  __bf16* vt = (__bf16*)d_out;

  const float scale = 0.17677669529663687f;  // 1/sqrt(32)

  build_tokmap_k<<<NTOK / 256, 256, 0, stream>>>(tokmap);
  expand_biasp_k<<<(NHEADS * 49 * 256) / 256, 256, 0, stream>>>(btab, relidx, biasex);
  pack_w_k<<<(DIM * QKV_DIM / 8) / 256, 256, 0, stream>>>(qkv_w, wqkvP, DIM, QKV_DIM, 6, DIM, scale);
  pack_w_k<<<(DIM * DIM / 8) / 256, 256, 0, stream>>>(proj_w, wprojP, DIM, DIM, 6, 0, 1.0f);
  pack_w_k<<<(DIM * HID / 8) / 256, 256, 0, stream>>>(fc1_w, wfc1P, DIM, HID, 6, 0, 1.0f);
  pack_w_k<<<(HID * DIM / 8) / 256, 256, 0, stream>>>(fc2_w, wfc2P, HID, DIM, 24, 0, 1.0f);
  scale_bias_k<<<(QKV_DIM + 255) / 256, 256, 0, stream>>>(qkv_b, qkvbS, QKV_DIM, DIM, scale);

  ln_k<float><<<NTOK / 4, 256, 0, stream>>>(x, n1g, n1b, tokens, tokmap);
  gemm_k<0><<<(NTOK / 256) * (QKV_DIM / 64), 256, 0, stream>>>(
      tokens, wqkvP, qkvbS, NTOK, QKV_DIM, DIM, qkvbuf, nullptr, nullptr, nullptr, nullptr);
  vtrans_k<<<NWIN, 384, 0, stream>>>(qkvbuf, vt);
  attn_k<<<NWIN * NHEADS * 7, 64, 0, stream>>>(qkvbuf, vt, biasex, attnout);
  gemm_k<1><<<(NTOK / 256) * (DIM / 64), 256, 0, stream>>>(
      attnout, wprojP, proj_b, NTOK, DIM, DIM, s1, nullptr, x, nullptr, tokmap);
  ln_k<__bf16><<<NTOK / 4, 256, 0, stream>>>(s1, n2g, n2b, tokens, nullptr);
  gemm_k<2><<<(NTOK / 256) * (HID / 64), 256, 0, stream>>>(
      tokens, wfc1P, fc1_b, NTOK, HID, DIM, h1, nullptr, nullptr, nullptr, nullptr);
  gemm_k<3><<<(NTOK / 256) * (DIM / 64), 256, 0, stream>>>(
      h1, wfc2P, fc2_b, NTOK, DIM, HID, nullptr, outp, nullptr, s1, nullptr);
}